// Round 6
// baseline (209.477 us; speedup 1.0000x reference)
//
#include <hip/hip_runtime.h>

// Problem constants (from setup_inputs): B=4, S=8, T=2048, R=256
#define T_N 2048
#define R_N 256
#define SLICES 32                     // B*S
#define NELEM (SLICES * T_N * R_N)    // 16,777,216 per tensor
#define INFV 3.0e38f
#define MIN_BLOCKS 2048               // 2048 x 256 threads, 8 float4/tensor/thread
#define MIN_THREADS (MIN_BLOCKS * 256)

// Deep-ILP streaming min: no grid-stride loop; 8 independent 16B loads per
// tensor per thread issued in two 4+4 batches -> ~8KB in flight per wave.
__global__ __launch_bounds__(256) void kmin(const float* __restrict__ x,
                                            const float* __restrict__ y,
                                            float* __restrict__ partial,
                                            float* __restrict__ out) {
    if (blockIdx.x == 0 && threadIdx.x < 4) out[threadIdx.x] = 0.0f;
    const int g0 = blockIdx.x * 256 + threadIdx.x;   // 0..524287
    const float4* __restrict__ x4 = (const float4*)x;
    const float4* __restrict__ y4 = (const float4*)y;
    float m0 = INFV, m1 = INFV;
    #pragma unroll
    for (int half = 0; half < 2; ++half) {
        float4 va[4], vb[4];
        #pragma unroll
        for (int it = 0; it < 4; ++it) {
            const int idx = g0 + (half * 4 + it) * MIN_THREADS;
            va[it] = x4[idx];
            vb[it] = y4[idx];
        }
        #pragma unroll
        for (int it = 0; it < 4; ++it) {
            m0 = fminf(m0, fminf(fminf(va[it].x, va[it].y), fminf(va[it].z, va[it].w)));
            m1 = fminf(m1, fminf(fminf(vb[it].x, vb[it].y), fminf(vb[it].z, vb[it].w)));
        }
    }
    float m = fminf(m0, m1);
    #pragma unroll
    for (int off = 32; off; off >>= 1) m = fminf(m, __shfl_down(m, off));
    __shared__ float sm[4];
    if ((threadIdx.x & 63) == 0) sm[threadIdx.x >> 6] = m;
    __syncthreads();
    if (threadIdx.x == 0)
        partial[blockIdx.x] = fminf(fminf(sm[0], sm[1]), fminf(sm[2], sm[3]));
}

// 1024-thread block = 4 problems (one float4 of r-columns), 4 waves/problem.
// 64 KiB LDS -> 2 blocks/CU; VGPR<=64 -> 32 waves/CU. Exact merged-quantile
// sum (validated R2/R4, absmax 0.0); merge refills only the advanced list.
__global__ __launch_bounds__(1024, 8) void kmain(const float* __restrict__ x,
                                                 const float* __restrict__ y,
                                                 const float* __restrict__ partial,
                                                 float* __restrict__ out) {
    __shared__ float L[8 * T_N];      // problem p: U at (2p)*T_N, V at (2p+1)*T_N
    __shared__ float red16[16];
    __shared__ float psum[4][2][4];   // [problem][list][wave-chunk] scan partials
    __shared__ float pacc[4][4];      // [problem][wave] result partials

    const int tid = threadIdx.x;
    const int w = tid >> 6;           // wave 0..15
    const int lane = tid & 63;

    // ---- phase 0: global min (partial[2048], two elements per thread) ----
    {
        float m = fminf(partial[tid], partial[tid + 1024]);
        #pragma unroll
        for (int off = 32; off; off >>= 1) m = fminf(m, __shfl_down(m, off));
        if (lane == 0) red16[w] = m;
    }
    __syncthreads();
    float mn = red16[0];
    #pragma unroll
    for (int k = 1; k < 16; ++k) mn = fminf(mn, red16[k]);
    const float sh = 1.1f * fminf(mn, 0.0f);

    // ---- XCD-aware remap: 4 blocks sharing a 64B global line -> same XCD ----
    const int blk = blockIdx.x;
    const int xcd = blk & 7;
    const int k2 = blk >> 3;
    const int sub = k2 & 3;
    const int rest = k2 >> 2;
    const int rt = (((rest & 1) << 3) + xcd) * 4 + sub;   // 0..63
    const int bs = rest >> 1;                              // 0..31
    const size_t base = (size_t)bs * (T_N * R_N) + (size_t)(rt * 4);

    // ---- staging: 4 columns of x and y (shifted) into linear LDS ----
    #pragma unroll
    for (int it = 0; it < 2; ++it) {
        const int t = tid + 1024 * it;
        const float4 a = *(const float4*)(x + base + (size_t)t * R_N);
        const float4 b = *(const float4*)(y + base + (size_t)t * R_N);
        L[0 * T_N + t] = a.x - sh;  L[2 * T_N + t] = a.y - sh;
        L[4 * T_N + t] = a.z - sh;  L[6 * T_N + t] = a.w - sh;
        L[1 * T_N + t] = b.x - sh;  L[3 * T_N + t] = b.y - sh;
        L[5 * T_N + t] = b.z - sh;  L[7 * T_N + t] = b.w - sh;
    }
    __syncthreads();

    const int p  = w >> 2;            // problem 0..3
    const int wl = w & 3;             // wave within problem
    const int pl = (wl << 6) | lane;  // problem-lane 0..255
    float* __restrict__ cu = &L[(2 * p) * T_N];
    float* __restrict__ cv = &L[(2 * p + 1) * T_N];

    // ---- scan: lane owns elems [8*pl, 8*pl+8) = quads 2pl, 2pl+1 ----
    {
        float4* __restrict__ cu4 = (float4*)cu;
        float4* __restrict__ cv4 = (float4*)cv;
        float4 u0 = cu4[2 * pl], u1 = cu4[2 * pl + 1];
        float4 v0 = cv4[2 * pl], v1 = cv4[2 * pl + 1];
        const float su = ((u0.x + u0.y) + (u0.z + u0.w)) + ((u1.x + u1.y) + (u1.z + u1.w));
        const float sv = ((v0.x + v0.y) + (v0.z + v0.w)) + ((v1.x + v1.y) + (v1.z + v1.w));
        float iu = su, iv = sv;
        #pragma unroll
        for (int off = 1; off < 64; off <<= 1) {
            const float a = __shfl_up(iu, off);
            const float b = __shfl_up(iv, off);
            if (lane >= off) { iu += a; iv += b; }
        }
        if (lane == 63) { psum[p][0][wl] = iu; psum[p][1][wl] = iv; }
        __syncthreads();
        float prefU = 0.f, totU = 0.f, prefV = 0.f, totV = 0.f;
        #pragma unroll
        for (int k = 0; k < 4; ++k) {
            const float a = psum[p][0][k], b = psum[p][1][k];
            totU += a; totV += b;
            if (k < wl) { prefU += a; prefV += b; }
        }
        const float invU = 1.0f / totU, invV = 1.0f / totV;
        float ru = prefU + (iu - su);
        float rv = prefV + (iv - sv);
        float4 o;
        ru += u0.x; o.x = ru * invU; ru += u0.y; o.y = ru * invU;
        ru += u0.z; o.z = ru * invU; ru += u0.w; o.w = ru * invU;
        cu4[2 * pl] = o;
        ru += u1.x; o.x = ru * invU; ru += u1.y; o.y = ru * invU;
        ru += u1.z; o.z = ru * invU; ru += u1.w; o.w = ru * invU;
        cu4[2 * pl + 1] = o;
        rv += v0.x; o.x = rv * invV; rv += v0.y; o.y = rv * invV;
        rv += v0.z; o.z = rv * invV; rv += v0.w; o.w = rv * invV;
        cv4[2 * pl] = o;
        rv += v1.x; o.x = rv * invV; rv += v1.y; o.y = rv * invV;
        rv += v1.z; o.z = rv * invV; rv += v1.w; o.w = rv * invV;
        cv4[2 * pl + 1] = o;
    }
    __syncthreads();

    // ---- co-rank partition: lane handles merged window [16*pl, 16*pl+16) ----
    const int d = pl << 4;
    int i = 0, j = 0;
    if (d > 0) {
        int lo = (d > T_N) ? (d - T_N) : 0;
        int hi = (d < T_N) ? d : T_N;
        while (lo < hi) {
            const int mid = (lo + hi) >> 1;
            if (cu[mid] <= cv[d - mid - 1]) lo = mid + 1; else hi = mid;
        }
        i = lo; j = d - lo;
    }
    float qprev = 0.0f;
    if (d > 0) {
        const float pa_ = (i > 0) ? cu[i - 1] : -INFV;
        const float pb_ = (j > 0) ? cv[j - 1] : -INFV;
        qprev = fmaxf(pa_, pb_);
    }

    float uv = (i < T_N) ? cu[min(i, T_N - 1)] : INFV;
    float vv = (j < T_N) ? cv[min(j, T_N - 1)] : INFV;

    float acc = 0.0f;
    #pragma unroll
    for (int s = 0; s < 16; ++s) {
        const bool take = (uv <= vv);
        const float q = take ? uv : vv;
        const float dd = (float)(min(i, T_N - 1) - min(j, T_N - 1));
        acc += (q - qprev) * dd * dd;
        qprev = q;
        i += take ? 1 : 0;
        j += take ? 0 : 1;
        if (s < 15) {
            const int ni = take ? i : j;                  // advanced index
            const float* bp = take ? cu : cv;
            const float r = bp[min(ni, T_N - 1)];
            const float rr = (ni < T_N) ? r : INFV;
            uv = take ? rr : uv;
            vv = take ? vv : rr;
        }
    }

    // ---- reduce: wave -> LDS -> one atomic per block ----
    #pragma unroll
    for (int off = 32; off; off >>= 1) acc += __shfl_down(acc, off);
    if (lane == 0) pacc[p][wl] = acc;
    __syncthreads();
    if (tid == 0) {
        float r = 0.f;
        #pragma unroll
        for (int pp = 0; pp < 4; ++pp)
            r += (pacc[pp][0] + pacc[pp][1]) + (pacc[pp][2] + pacc[pp][3]);
        atomicAdd(&out[bs >> 3], r * (1.0f / ((float)T_N * (float)T_N)));
    }
}

extern "C" void kernel_launch(void* const* d_in, const int* in_sizes, int n_in,
                              void* d_out, int out_size, void* d_ws, size_t ws_size,
                              hipStream_t stream) {
    const float* x = (const float*)d_in[0];
    const float* y = (const float*)d_in[1];
    float* out = (float*)d_out;
    float* partial = (float*)d_ws;   // MIN_BLOCKS floats (8 KiB)

    kmin<<<MIN_BLOCKS, 256, 0, stream>>>(x, y, partial, out);
    kmain<<<SLICES * 64, 1024, 0, stream>>>(x, y, partial, out);
}